// Round 7
// baseline (93.703 us; speedup 1.0000x reference)
//
#include <hip/hip_runtime.h>
#include <stdint.h>

#define B 512
#define D 128
#define HALFC 131072u
#define SUB 4
#define NSLOT (SUB * 4)

__device__ __forceinline__ uint32_t rotl32(uint32_t x, uint32_t r) {
  return (x << r) | (x >> (32u - r));
}

// Exact JAX/XLA threefry2x32 (20 rounds, key-schedule injections every 4).
__device__ __forceinline__ void threefry2x32(uint32_t k0, uint32_t k1,
                                             uint32_t x0, uint32_t x1,
                                             uint32_t& y0, uint32_t& y1) {
  uint32_t k2 = k0 ^ k1 ^ 0x1BD11BDAu;
  x0 += k0; x1 += k1;
#define TF_R(r) { x0 += x1; x1 = rotl32(x1, r); x1 ^= x0; }
  TF_R(13) TF_R(15) TF_R(26) TF_R(6)
  x0 += k1; x1 += k2 + 1u;
  TF_R(17) TF_R(29) TF_R(16) TF_R(24)
  x0 += k2; x1 += k0 + 2u;
  TF_R(13) TF_R(15) TF_R(26) TF_R(6)
  x0 += k0; x1 += k1 + 3u;
  TF_R(17) TF_R(29) TF_R(16) TF_R(24)
  x0 += k1; x1 += k2 + 4u;
  TF_R(13) TF_R(15) TF_R(26) TF_R(6)
  x0 += k2; x1 += k0 + 5u;
#undef TF_R
  y0 = x0; y1 = x1;
}

// Two independent threefry chains interleaved (ILP for the serial rounds).
__device__ __forceinline__ void threefry2x32_dual(
    uint32_t k0, uint32_t k1, uint32_t a0, uint32_t a1, uint32_t b0,
    uint32_t b1, uint32_t& ya0, uint32_t& ya1, uint32_t& yb0, uint32_t& yb1) {
  uint32_t k2 = k0 ^ k1 ^ 0x1BD11BDAu;
  a0 += k0; a1 += k1; b0 += k0; b1 += k1;
#define TF_R2(r) { a0 += a1; a1 = rotl32(a1, r); a1 ^= a0; \
                   b0 += b1; b1 = rotl32(b1, r); b1 ^= b0; }
  TF_R2(13) TF_R2(15) TF_R2(26) TF_R2(6)
  a0 += k1; a1 += k2 + 1u; b0 += k1; b1 += k2 + 1u;
  TF_R2(17) TF_R2(29) TF_R2(16) TF_R2(24)
  a0 += k2; a1 += k0 + 2u; b0 += k2; b1 += k0 + 2u;
  TF_R2(13) TF_R2(15) TF_R2(26) TF_R2(6)
  a0 += k0; a1 += k1 + 3u; b0 += k0; b1 += k1 + 3u;
  TF_R2(17) TF_R2(29) TF_R2(16) TF_R2(24)
  a0 += k1; a1 += k2 + 4u; b0 += k1; b1 += k2 + 4u;
  TF_R2(13) TF_R2(15) TF_R2(26) TF_R2(6)
  a0 += k2; a1 += k0 + 5u; b0 += k2; b1 += k0 + 5u;
#undef TF_R2
  ya0 = a0; ya1 = a1; yb0 = b0; yb1 = b1;
}

// K1: tiled dist "GEMM". Block (ti,tj) computes a 32x32 tile of dist from two
// coalesced-staged 32x128 LDS panels (fused sq). Block 0 also computes the
// 512 anchor keys and zeroes the global accumulators.
__global__ __launch_bounds__(256) void dist_kernel(
    const float* __restrict__ emb, float* __restrict__ dist,
    uint32_t* __restrict__ keys0, uint32_t* __restrict__ keys1,
    double* __restrict__ gsum, unsigned int* __restrict__ gcnt,
    unsigned int* __restrict__ gdone) {
  __shared__ float As[32][132];  // pad 132: bank = (4r + k) % 32, conflict-free
  __shared__ float Bs[32][132];
  __shared__ float sqa[32], sqb[32];
  int bid = blockIdx.x;
  int ti = bid >> 4, tj = bid & 15;
  int t = threadIdx.x;

  // coalesced stage: 32 rows x 128 floats = 1024 float4 per panel
  const float4* ga = reinterpret_cast<const float4*>(emb + (size_t)ti * 32 * D);
  const float4* gb = reinterpret_cast<const float4*>(emb + (size_t)tj * 32 * D);
  #pragma unroll
  for (int k = 0; k < 4; ++k) {
    int idx = t + k * 256;   // float4 index 0..1023
    int r = idx >> 5;        // 32 float4 per row
    int c4 = idx & 31;
    *reinterpret_cast<float4*>(&As[r][c4 * 4]) = ga[idx];
    *reinterpret_cast<float4*>(&Bs[r][c4 * 4]) = gb[idx];
  }
  __syncthreads();

  // fused sq: 64 rows (32 A + 32 B), 4 threads/row of 32 floats each
  {
    int row = t >> 2, seg = t & 3;
    const float* src = (row < 32) ? &As[row][seg * 32] : &Bs[row - 32][seg * 32];
    float s = 0.f;
    #pragma unroll
    for (int m = 0; m < 32; ++m) { float v = src[m]; s += v * v; }
    s += __shfl_xor(s, 1);
    s += __shfl_xor(s, 2);
    if (seg == 0) { if (row < 32) sqa[row] = s; else sqb[row - 32] = s; }
  }

  // dots: thread (r = t>>3, g = t&7) computes cols c = g + 8j, j=0..3
  int r = t >> 3, g = t & 7;
  const float4* A4 = reinterpret_cast<const float4*>(&As[r][0]);
  const float4* B0 = reinterpret_cast<const float4*>(&Bs[g][0]);
  const float4* B1 = reinterpret_cast<const float4*>(&Bs[g + 8][0]);
  const float4* B2 = reinterpret_cast<const float4*>(&Bs[g + 16][0]);
  const float4* B3 = reinterpret_cast<const float4*>(&Bs[g + 24][0]);
  float acc0 = 0.f, acc1 = 0.f, acc2 = 0.f, acc3 = 0.f;
  #pragma unroll 8
  for (int k4 = 0; k4 < 32; ++k4) {
    float4 a = A4[k4];
    float4 b0 = B0[k4], b1 = B1[k4], b2 = B2[k4], b3 = B3[k4];
    acc0 += a.x * b0.x + a.y * b0.y + a.z * b0.z + a.w * b0.w;
    acc1 += a.x * b1.x + a.y * b1.y + a.z * b1.z + a.w * b1.w;
    acc2 += a.x * b2.x + a.y * b2.y + a.z * b2.z + a.w * b2.w;
    acc3 += a.x * b3.x + a.y * b3.y + a.z * b3.z + a.w * b3.w;
  }
  __syncthreads();  // sqa/sqb ready
  float sa = sqa[r];
  float* drow = dist + (size_t)(ti * 32 + r) * B + tj * 32;
  drow[g]      = sqrtf(fmaxf(sa + sqb[g]      - 2.f * acc0, 0.f));
  drow[g + 8]  = sqrtf(fmaxf(sa + sqb[g + 8]  - 2.f * acc1, 0.f));
  drow[g + 16] = sqrtf(fmaxf(sa + sqb[g + 16] - 2.f * acc2, 0.f));
  drow[g + 24] = sqrtf(fmaxf(sa + sqb[g + 24] - 2.f * acc3, 0.f));

  // block 0 tail: anchor keys + zero accumulators
  if (bid == 0) {
    if (t == 0) { *gsum = 0.0; *gcnt = 0u; *gdone = 0u; }
    #pragma unroll
    for (int pp = 0; pp < 2; ++pp) {
      int p = t + pp * 256;
      uint32_t i0 = 2u * (uint32_t)p, i1 = i0 + 1u;
      uint32_t a0, a1, b0, b1;
      if (p < 256) {
        threefry2x32(0u, 42u, i0, i0 + 512u, a0, a1);
        threefry2x32(0u, 42u, i1, i1 + 512u, b0, b1);
        keys0[p] = a0; keys1[p] = b0;
      } else {
        threefry2x32(0u, 42u, i0 - 512u, i0, a0, a1);
        threefry2x32(0u, 42u, i1 - 512u, i1, b0, b1);
        keys0[p] = a1; keys1[p] = b1;
      }
    }
  }
}

// K2 (row-major): block = (row i, sub). drow staged once in LDS; dd8/negm/
// hard-argmin row-invariant in registers; anchors share them. Per anchor:
// compaction + dual-threefry + packed-u32 lex argmax (bits desc, j asc).
// Last-arriving block finalizes out = sum/cnt.
__global__ __launch_bounds__(256) void triplet_kernel(
    const float* __restrict__ dist, const int* __restrict__ labels,
    const uint32_t* __restrict__ keys0, const uint32_t* __restrict__ keys1,
    double* __restrict__ gsum, unsigned int* __restrict__ gcnt,
    unsigned int* __restrict__ gdone, float* __restrict__ out) {
  __shared__ float drow[B];
  __shared__ unsigned short slab[B];
  __shared__ unsigned short list_sh[B];
  __shared__ unsigned short cand[4][B];
  __shared__ int nlist_sh;
  __shared__ double lsum[4];
  __shared__ unsigned int lcnt[4];

  int bid = blockIdx.x;
  int i = bid >> 2;  // SUB = 4
  int sub = bid & 3;
  int t = threadIdx.x;
  slab[t] = (unsigned short)labels[t];
  slab[t + 256] = (unsigned short)labels[t + 256];
  const float* __restrict__ dg = dist + (size_t)i * B;
  drow[t] = dg[t];
  drow[t + 256] = dg[t + 256];
  __syncthreads();

  int wave = t >> 6, lane = t & 63;
  unsigned long long lmask_lt = (1ull << lane) - 1ull;
  unsigned short lab_i = slab[i];

  // wave 0: ascending list of same-label anchors p (includes i; skipped later)
  if (wave == 0) {
    int n = 0;
    #pragma unroll
    for (int c = 0; c < 8; ++c) {
      int r = c * 64 + lane;
      bool v = (slab[r] == lab_i);
      unsigned long long mk = __ballot(v);
      if (v) list_sh[n + __popcll(mk & lmask_lt)] = (unsigned short)r;
      n += __popcll(mk);
    }
    if (lane == 0) nlist_sh = (n == B) ? 0 : n;  // n==B -> no negatives
  }

  // row-invariant per-lane data + in-block hard-negative argmin
  float dd8[8];
  uint32_t negm = 0;
  unsigned long long hkey = ~0ull;
  #pragma unroll
  for (int jc = 0; jc < 8; ++jc) {
    int j = jc * 64 + lane;
    dd8[jc] = drow[j];
    bool neg = (slab[j] != lab_i);
    negm |= (uint32_t)neg << jc;
    if (neg) {
      unsigned long long k =
          (((unsigned long long)__float_as_uint(dd8[jc])) << 9) | (unsigned)j;
      if (k < hkey) hkey = k;
    }
  }
  #pragma unroll
  for (int off = 32; off; off >>= 1) {
    unsigned long long o = __shfl_xor(hkey, off);
    if (o < hkey) hkey = o;
  }
  int hard = (int)(hkey & 0x1FFu);  // valid whenever any negative exists
  uint32_t rowbase = (uint32_t)((i & 255) * B);
  bool take_hi = (i >= 256);
  __syncthreads();  // list_sh / nlist_sh ready

  int nlist = nlist_sh;
  unsigned short* wcand = cand[wave];
  double wsum = 0.0;
  unsigned int wcnt = 0;

  for (int k = sub * 4 + wave; k < nlist; k += NSLOT) {
    int p = list_sh[k];
    if (p == i) continue;
    p = __builtin_amdgcn_readfirstlane(p);  // wave-uniform
    uint32_t kp0 = keys0[p], kp1 = keys1[p];
    float pos_d = drow[p];
    float hiv = pos_d + 1.0f;  // margin = 1.0

    int nc = 0;
    #pragma unroll
    for (int jc = 0; jc < 8; ++jc) {
      bool m = ((negm >> jc) & 1u) && (dd8[jc] > pos_d) && (dd8[jc] < hiv);
      unsigned long long mk = __ballot(m);
      if (m) wcand[nc + __popcll(mk & lmask_lt)] =
          (unsigned short)(jc * 64 + lane);
      nc += __popcll(mk);
    }

    int idx;
    if (nc > 0) {
      // packed key: (bits23 << 9) | (511 - j); max -> max bits, tie -> min j
      uint32_t best = 0u;
      for (int c = lane; c < nc; c += 128) {
        int j1 = wcand[c];
        int c2 = c + 64;
        int j2 = (c2 < nc) ? wcand[c2] : j1;
        uint32_t ya0, ya1, yb0, yb1;
        threefry2x32_dual(kp0, kp1,
                          rowbase + (uint32_t)j1, rowbase + (uint32_t)j1 + HALFC,
                          rowbase + (uint32_t)j2, rowbase + (uint32_t)j2 + HALFC,
                          ya0, ya1, yb0, yb1);
        uint32_t y1v = take_hi ? ya1 : ya0;
        uint32_t key1 = (y1v & 0xFFFFFE00u) | (uint32_t)(511 - j1);
        if (key1 > best) best = key1;
        if (c2 < nc) {
          uint32_t y2v = take_hi ? yb1 : yb0;
          uint32_t key2 = (y2v & 0xFFFFFE00u) | (uint32_t)(511 - j2);
          if (key2 > best) best = key2;
        }
      }
      #pragma unroll
      for (int off = 32; off; off >>= 1) {
        uint32_t ob = (uint32_t)__shfl_xor((int)best, off);
        if (ob > best) best = ob;
      }
      idx = 511 - (int)(best & 0x1FFu);
    } else {
      idx = hard;
    }
    float neg_d = drow[idx];
    float tl = pos_d - neg_d + 1.0f;
    if (tl > 0.f) { wsum += (double)tl; wcnt++; }
  }

  if (lane == 0) { lsum[wave] = wsum; lcnt[wave] = wcnt; }
  __syncthreads();
  if (t == 0) {
    double bsum = lsum[0] + lsum[1] + lsum[2] + lsum[3];
    unsigned int bcnt = lcnt[0] + lcnt[1] + lcnt[2] + lcnt[3];
    if (bsum != 0.0) atomicAdd(gsum, bsum);
    if (bcnt) atomicAdd(gcnt, bcnt);
    __threadfence();
    unsigned int old = atomicAdd(gdone, 1u);
    if (old == (unsigned int)(gridDim.x - 1)) {
      __threadfence();
      double s = atomicAdd(gsum, 0.0);       // coherent read-back
      unsigned int c = atomicAdd(gcnt, 0u);  // coherent read-back
      out[0] = c ? (float)(s / (double)c) : 0.0f;
    }
  }
}

extern "C" void kernel_launch(void* const* d_in, const int* in_sizes, int n_in,
                              void* d_out, int out_size, void* d_ws, size_t ws_size,
                              hipStream_t stream) {
  const float* emb = (const float*)d_in[0];
  const int* labels = (const int*)d_in[1];
  float* out = (float*)d_out;
  char* ws = (char*)d_ws;

  float* dist = (float*)ws;                              // 1 MB
  uint32_t* keys0 = (uint32_t*)(ws + 1048576);           // 2 KB
  uint32_t* keys1 = (uint32_t*)(ws + 1048576 + 2048);    // 2 KB
  double* gsum = (double*)(ws + 1048576 + 4096);         // 8 B
  unsigned int* gcnt = (unsigned int*)(ws + 1048576 + 4096 + 8);
  unsigned int* gdone = (unsigned int*)(ws + 1048576 + 4096 + 12);

  dist_kernel<<<256, 256, 0, stream>>>(emb, dist, keys0, keys1, gsum, gcnt,
                                       gdone);
  triplet_kernel<<<B * SUB, 256, 0, stream>>>(dist, labels, keys0, keys1,
                                              gsum, gcnt, gdone, out);
}

// Round 8
// 41.335 us; speedup vs baseline: 2.2669x; 2.2669x over previous
//
#include <hip/hip_runtime.h>
#include <stdint.h>

#define B 512
#define D 128
#define HALFC 131072u
#define SUB 4
#define NSLOT (SUB * 4)
#define NPART (B * SUB)

__device__ __forceinline__ uint32_t rotl32(uint32_t x, uint32_t r) {
  return (x << r) | (x >> (32u - r));
}

// Exact JAX/XLA threefry2x32 (20 rounds, key-schedule injections every 4).
__device__ __forceinline__ void threefry2x32(uint32_t k0, uint32_t k1,
                                             uint32_t x0, uint32_t x1,
                                             uint32_t& y0, uint32_t& y1) {
  uint32_t k2 = k0 ^ k1 ^ 0x1BD11BDAu;
  x0 += k0; x1 += k1;
#define TF_R(r) { x0 += x1; x1 = rotl32(x1, r); x1 ^= x0; }
  TF_R(13) TF_R(15) TF_R(26) TF_R(6)
  x0 += k1; x1 += k2 + 1u;
  TF_R(17) TF_R(29) TF_R(16) TF_R(24)
  x0 += k2; x1 += k0 + 2u;
  TF_R(13) TF_R(15) TF_R(26) TF_R(6)
  x0 += k0; x1 += k1 + 3u;
  TF_R(17) TF_R(29) TF_R(16) TF_R(24)
  x0 += k1; x1 += k2 + 4u;
  TF_R(13) TF_R(15) TF_R(26) TF_R(6)
  x0 += k2; x1 += k0 + 5u;
#undef TF_R
  y0 = x0; y1 = x1;
}

// Two independent threefry chains interleaved (ILP for the serial rounds).
__device__ __forceinline__ void threefry2x32_dual(
    uint32_t k0, uint32_t k1, uint32_t a0, uint32_t a1, uint32_t b0,
    uint32_t b1, uint32_t& ya0, uint32_t& ya1, uint32_t& yb0, uint32_t& yb1) {
  uint32_t k2 = k0 ^ k1 ^ 0x1BD11BDAu;
  a0 += k0; a1 += k1; b0 += k0; b1 += k1;
#define TF_R2(r) { a0 += a1; a1 = rotl32(a1, r); a1 ^= a0; \
                   b0 += b1; b1 = rotl32(b1, r); b1 ^= b0; }
  TF_R2(13) TF_R2(15) TF_R2(26) TF_R2(6)
  a0 += k1; a1 += k2 + 1u; b0 += k1; b1 += k2 + 1u;
  TF_R2(17) TF_R2(29) TF_R2(16) TF_R2(24)
  a0 += k2; a1 += k0 + 2u; b0 += k2; b1 += k0 + 2u;
  TF_R2(13) TF_R2(15) TF_R2(26) TF_R2(6)
  a0 += k0; a1 += k1 + 3u; b0 += k0; b1 += k1 + 3u;
  TF_R2(17) TF_R2(29) TF_R2(16) TF_R2(24)
  a0 += k1; a1 += k2 + 4u; b0 += k1; b1 += k2 + 4u;
  TF_R2(13) TF_R2(15) TF_R2(26) TF_R2(6)
  a0 += k2; a1 += k0 + 5u; b0 += k2; b1 += k0 + 5u;
#undef TF_R2
  ya0 = a0; ya1 = a1; yb0 = b0; yb1 = b1;
}

// K1: tiled dist "GEMM". Block (ti,tj) computes a 32x32 tile of dist from two
// coalesced-staged 32x128 LDS panels (fused sq). Block 0 also computes the
// 512 anchor keys.
__global__ __launch_bounds__(256) void dist_kernel(
    const float* __restrict__ emb, float* __restrict__ dist,
    uint32_t* __restrict__ keys0, uint32_t* __restrict__ keys1) {
  __shared__ float As[32][132];  // pad 132: bank = (4r + k) % 32, conflict-free
  __shared__ float Bs[32][132];
  __shared__ float sqa[32], sqb[32];
  int bid = blockIdx.x;
  int ti = bid >> 4, tj = bid & 15;
  int t = threadIdx.x;

  // coalesced stage: 32 rows x 128 floats = 1024 float4 per panel
  const float4* ga = reinterpret_cast<const float4*>(emb + (size_t)ti * 32 * D);
  const float4* gb = reinterpret_cast<const float4*>(emb + (size_t)tj * 32 * D);
  #pragma unroll
  for (int k = 0; k < 4; ++k) {
    int idx = t + k * 256;   // float4 index 0..1023
    int r = idx >> 5;        // 32 float4 per row
    int c4 = idx & 31;
    *reinterpret_cast<float4*>(&As[r][c4 * 4]) = ga[idx];
    *reinterpret_cast<float4*>(&Bs[r][c4 * 4]) = gb[idx];
  }
  __syncthreads();

  // fused sq: 64 rows (32 A + 32 B), 4 threads/row of 32 floats each
  {
    int row = t >> 2, seg = t & 3;
    const float* src = (row < 32) ? &As[row][seg * 32] : &Bs[row - 32][seg * 32];
    float s = 0.f;
    #pragma unroll
    for (int m = 0; m < 32; ++m) { float v = src[m]; s += v * v; }
    s += __shfl_xor(s, 1);
    s += __shfl_xor(s, 2);
    if (seg == 0) { if (row < 32) sqa[row] = s; else sqb[row - 32] = s; }
  }

  // dots: thread (r = t>>3, g = t&7) computes cols c = g + 8j, j=0..3
  int r = t >> 3, g = t & 7;
  const float4* A4 = reinterpret_cast<const float4*>(&As[r][0]);
  const float4* B0 = reinterpret_cast<const float4*>(&Bs[g][0]);
  const float4* B1 = reinterpret_cast<const float4*>(&Bs[g + 8][0]);
  const float4* B2 = reinterpret_cast<const float4*>(&Bs[g + 16][0]);
  const float4* B3 = reinterpret_cast<const float4*>(&Bs[g + 24][0]);
  float acc0 = 0.f, acc1 = 0.f, acc2 = 0.f, acc3 = 0.f;
  #pragma unroll 8
  for (int k4 = 0; k4 < 32; ++k4) {
    float4 a = A4[k4];
    float4 b0 = B0[k4], b1 = B1[k4], b2 = B2[k4], b3 = B3[k4];
    acc0 += a.x * b0.x + a.y * b0.y + a.z * b0.z + a.w * b0.w;
    acc1 += a.x * b1.x + a.y * b1.y + a.z * b1.z + a.w * b1.w;
    acc2 += a.x * b2.x + a.y * b2.y + a.z * b2.z + a.w * b2.w;
    acc3 += a.x * b3.x + a.y * b3.y + a.z * b3.z + a.w * b3.w;
  }
  __syncthreads();  // sqa/sqb ready
  float sa = sqa[r];
  float* drow = dist + (size_t)(ti * 32 + r) * B + tj * 32;
  drow[g]      = sqrtf(fmaxf(sa + sqb[g]      - 2.f * acc0, 0.f));
  drow[g + 8]  = sqrtf(fmaxf(sa + sqb[g + 8]  - 2.f * acc1, 0.f));
  drow[g + 16] = sqrtf(fmaxf(sa + sqb[g + 16] - 2.f * acc2, 0.f));
  drow[g + 24] = sqrtf(fmaxf(sa + sqb[g + 24] - 2.f * acc3, 0.f));

  // block 0 tail: anchor keys
  // keys[p] from split(key(42), 512): out[q] = q<512 ? y0(q,q+512) : y1(q-512,q)
  if (bid == 0) {
    #pragma unroll
    for (int pp = 0; pp < 2; ++pp) {
      int p = t + pp * 256;
      uint32_t i0 = 2u * (uint32_t)p, i1 = i0 + 1u;
      uint32_t a0, a1, b0, b1;
      if (p < 256) {
        threefry2x32(0u, 42u, i0, i0 + 512u, a0, a1);
        threefry2x32(0u, 42u, i1, i1 + 512u, b0, b1);
        keys0[p] = a0; keys1[p] = b0;
      } else {
        threefry2x32(0u, 42u, i0 - 512u, i0, a0, a1);
        threefry2x32(0u, 42u, i1 - 512u, i1, b0, b1);
        keys0[p] = a1; keys1[p] = b1;
      }
    }
  }
}

// K2 (row-major): block = (row i, sub). drow staged once in LDS; dd8/negm/
// hard-argmin row-invariant in registers; anchors share them. Per anchor:
// compaction + dual-threefry + packed-u32 lex argmax (bits desc, j asc).
// Per-block partials write (NO contended atomics / fences — round-7 lesson).
__global__ __launch_bounds__(256) void triplet_kernel(
    const float* __restrict__ dist, const int* __restrict__ labels,
    const uint32_t* __restrict__ keys0, const uint32_t* __restrict__ keys1,
    double* __restrict__ partials, int* __restrict__ pcnt) {
  __shared__ float drow[B];
  __shared__ unsigned short slab[B];
  __shared__ unsigned short list_sh[B];
  __shared__ unsigned short cand[4][B];
  __shared__ int nlist_sh;
  __shared__ double lsum[4];
  __shared__ unsigned int lcnt[4];

  int bid = blockIdx.x;
  int i = bid >> 2;  // SUB = 4
  int sub = bid & 3;
  int t = threadIdx.x;
  slab[t] = (unsigned short)labels[t];
  slab[t + 256] = (unsigned short)labels[t + 256];
  const float* __restrict__ dg = dist + (size_t)i * B;
  drow[t] = dg[t];
  drow[t + 256] = dg[t + 256];
  __syncthreads();

  int wave = t >> 6, lane = t & 63;
  unsigned long long lmask_lt = (1ull << lane) - 1ull;
  unsigned short lab_i = slab[i];

  // wave 0: ascending list of same-label anchors p (includes i; skipped later)
  if (wave == 0) {
    int n = 0;
    #pragma unroll
    for (int c = 0; c < 8; ++c) {
      int r = c * 64 + lane;
      bool v = (slab[r] == lab_i);
      unsigned long long mk = __ballot(v);
      if (v) list_sh[n + __popcll(mk & lmask_lt)] = (unsigned short)r;
      n += __popcll(mk);
    }
    if (lane == 0) nlist_sh = (n == B) ? 0 : n;  // n==B -> no negatives
  }

  // row-invariant per-lane data + in-block hard-negative argmin
  float dd8[8];
  uint32_t negm = 0;
  unsigned long long hkey = ~0ull;
  #pragma unroll
  for (int jc = 0; jc < 8; ++jc) {
    int j = jc * 64 + lane;
    dd8[jc] = drow[j];
    bool neg = (slab[j] != lab_i);
    negm |= (uint32_t)neg << jc;
    if (neg) {
      unsigned long long k =
          (((unsigned long long)__float_as_uint(dd8[jc])) << 9) | (unsigned)j;
      if (k < hkey) hkey = k;
    }
  }
  #pragma unroll
  for (int off = 32; off; off >>= 1) {
    unsigned long long o = __shfl_xor(hkey, off);
    if (o < hkey) hkey = o;
  }
  int hard = (int)(hkey & 0x1FFu);  // valid whenever any negative exists
  uint32_t rowbase = (uint32_t)((i & 255) * B);
  bool take_hi = (i >= 256);
  __syncthreads();  // list_sh / nlist_sh ready

  int nlist = nlist_sh;
  unsigned short* wcand = cand[wave];
  double wsum = 0.0;
  unsigned int wcnt = 0;

  for (int k = sub * 4 + wave; k < nlist; k += NSLOT) {
    int p = list_sh[k];
    if (p == i) continue;
    p = __builtin_amdgcn_readfirstlane(p);  // wave-uniform
    uint32_t kp0 = keys0[p], kp1 = keys1[p];
    float pos_d = drow[p];
    float hiv = pos_d + 1.0f;  // margin = 1.0

    int nc = 0;
    #pragma unroll
    for (int jc = 0; jc < 8; ++jc) {
      bool m = ((negm >> jc) & 1u) && (dd8[jc] > pos_d) && (dd8[jc] < hiv);
      unsigned long long mk = __ballot(m);
      if (m) wcand[nc + __popcll(mk & lmask_lt)] =
          (unsigned short)(jc * 64 + lane);
      nc += __popcll(mk);
    }

    int idx;
    if (nc > 0) {
      // packed key: (bits23 << 9) | (511 - j); max -> max bits, tie -> min j
      uint32_t best = 0u;
      for (int c = lane; c < nc; c += 128) {
        int j1 = wcand[c];
        int c2 = c + 64;
        int j2 = (c2 < nc) ? wcand[c2] : j1;
        uint32_t ya0, ya1, yb0, yb1;
        threefry2x32_dual(kp0, kp1,
                          rowbase + (uint32_t)j1, rowbase + (uint32_t)j1 + HALFC,
                          rowbase + (uint32_t)j2, rowbase + (uint32_t)j2 + HALFC,
                          ya0, ya1, yb0, yb1);
        uint32_t y1v = take_hi ? ya1 : ya0;
        uint32_t key1 = (y1v & 0xFFFFFE00u) | (uint32_t)(511 - j1);
        if (key1 > best) best = key1;
        if (c2 < nc) {
          uint32_t y2v = take_hi ? yb1 : yb0;
          uint32_t key2 = (y2v & 0xFFFFFE00u) | (uint32_t)(511 - j2);
          if (key2 > best) best = key2;
        }
      }
      #pragma unroll
      for (int off = 32; off; off >>= 1) {
        uint32_t ob = (uint32_t)__shfl_xor((int)best, off);
        if (ob > best) best = ob;
      }
      idx = 511 - (int)(best & 0x1FFu);
    } else {
      idx = hard;
    }
    float neg_d = drow[idx];
    float tl = pos_d - neg_d + 1.0f;
    if (tl > 0.f) { wsum += (double)tl; wcnt++; }
  }

  if (lane == 0) { lsum[wave] = wsum; lcnt[wave] = wcnt; }
  __syncthreads();
  if (t == 0) {
    partials[bid] = lsum[0] + lsum[1] + lsum[2] + lsum[3];
    pcnt[bid] = (int)(lcnt[0] + lcnt[1] + lcnt[2] + lcnt[3]);
  }
}

// K3: deterministic fixed-order reduction of the 2048 block partials.
__global__ __launch_bounds__(256) void finalize_kernel(
    const double* __restrict__ partials, const int* __restrict__ pcnt,
    float* __restrict__ out) {
  __shared__ double ss[256];
  __shared__ int sc[256];
  int t = threadIdx.x;
  double s = 0.0;
  int c = 0;
  for (int k = t; k < NPART; k += 256) { s += partials[k]; c += pcnt[k]; }
  ss[t] = s; sc[t] = c;
  __syncthreads();
  for (int st = 128; st; st >>= 1) {
    if (t < st) { ss[t] += ss[t + st]; sc[t] += sc[t + st]; }
    __syncthreads();
  }
  if (t == 0) out[0] = sc[0] ? (float)(ss[0] / (double)sc[0]) : 0.0f;
}

extern "C" void kernel_launch(void* const* d_in, const int* in_sizes, int n_in,
                              void* d_out, int out_size, void* d_ws, size_t ws_size,
                              hipStream_t stream) {
  const float* emb = (const float*)d_in[0];
  const int* labels = (const int*)d_in[1];
  float* out = (float*)d_out;
  char* ws = (char*)d_ws;

  float* dist = (float*)ws;                            // 1 MB
  uint32_t* keys0 = (uint32_t*)(ws + 1048576);         // 2 KB
  uint32_t* keys1 = (uint32_t*)(ws + 1048576 + 2048);  // 2 KB
  double* partials = (double*)(ws + 1048576 + 4096);   // 16 KB
  int* pcnt = (int*)(ws + 1048576 + 4096 + 16384);     // 8 KB

  dist_kernel<<<256, 256, 0, stream>>>(emb, dist, keys0, keys1);
  triplet_kernel<<<B * SUB, 256, 0, stream>>>(dist, labels, keys0, keys1,
                                              partials, pcnt);
  finalize_kernel<<<1, 256, 0, stream>>>(partials, pcnt, out);
}